// Round 15
// baseline (302.685 us; speedup 1.0000x reference)
//
#include <hip/hip_runtime.h>
#include <math.h>

static constexpr int NN = 100000;   // nodes
static constexpr int NE = 1600000;  // edges
static constexpr float BN_EPS = 1e-5f;
static constexpr int K_BKT = (NN + 255) / 256;   // 391 coarse buckets (dst>>8)
static constexpr int CH = 4096;                  // edges per partition block
static constexpr int CAP = 6144;                 // fixed slots per bucket (mean 4096)

typedef __attribute__((ext_vector_type(8))) short bf16x8;
typedef __attribute__((ext_vector_type(4))) float f32x4;

// bf16 helpers (RNE pack, exact unpack)
__device__ __forceinline__ unsigned short f2bf(float f) {
    unsigned int u = __float_as_uint(f);
    u += 0x7fffu + ((u >> 16) & 1u);
    return (unsigned short)(u >> 16);
}
__device__ __forceinline__ float bf2f(unsigned short b) {
    return __uint_as_float(((unsigned int)b) << 16);
}

// ---------------- partition: bucket-grouped staged writes, fixed-capacity ----
// Single pass over edges (register-cached); write-out via flat per-element
// binary search so all 64 lanes stay active (runs are only ~10 edges).
__global__ __launch_bounds__(256) void partition_edges(
    const int* __restrict__ src, const int* __restrict__ dst,
    int* __restrict__ bcur, int* __restrict__ staged, int e)
{
    __shared__ int s_out[CH];       // 16 KB
    __shared__ int cntL[512];       // counts -> inclusive scan
    __shared__ int gbase[K_BKT];
    __shared__ int curL[K_BKT];

    int tid = threadIdx.x;
    int c0 = blockIdx.x * CH;
    int cend = min(c0 + CH, e);
    int nE = cend - c0;

    for (int i = tid; i < 512; i += 256) cntL[i] = 0;
    __syncthreads();

    int sreg[16], dreg[16];
#pragma unroll
    for (int k = 0; k < 16; ++k) {
        int i = c0 + tid + k * 256;
        if (i < cend) {
            sreg[k] = src[i];
            dreg[k] = dst[i];
            atomicAdd(&cntL[((unsigned)dreg[k]) >> 8], 1);
        }
    }
    __syncthreads();

    // reserve contiguous runs inside each bucket's fixed region
    for (int b = tid; b < K_BKT; b += 256) {
        int c = cntL[b];
        gbase[b] = (c > 0) ? (b * CAP + atomicAdd(&bcur[b], c)) : 0;
    }
    __syncthreads();

    // inclusive scan of cntL (512, 2 elems/thread Hillis-Steele)
    for (int d = 1; d < 512; d <<= 1) {
        int x0 = (tid >= d) ? cntL[tid - d] : 0;
        int i1 = tid + 256;
        int x1 = (i1 >= d) ? cntL[i1 - d] : 0;
        __syncthreads();
        cntL[tid] += x0;
        cntL[i1]  += x1;
        __syncthreads();
    }
    for (int b = tid; b < K_BKT; b += 256)
        curL[b] = (b == 0) ? 0 : cntL[b - 1];
    __syncthreads();

    // reorder into LDS grouped by bucket (registers, no re-read)
#pragma unroll
    for (int k = 0; k < 16; ++k) {
        int i = c0 + tid + k * 256;
        if (i < cend) {
            int b = ((unsigned)dreg[k]) >> 8;
            int r = atomicAdd(&curL[b], 1);
            s_out[r] = sreg[k] | ((dreg[k] & 255) << 24);
        }
    }
    __syncthreads();

    // flat write-out: element i -> bucket via binary search on scanned cntL
    for (int i = tid; i < nE; i += 256) {
        int val = s_out[i];
        int b = 0;
#pragma unroll
        for (int step = 256; step >= 1; step >>= 1) {
            int nb = b + step;
            if (nb <= 512 && cntL[nb - 1] <= i) b = nb;
        }
        int lo = (b == 0) ? 0 : cntL[b - 1];
        __builtin_nontemporal_store(val, &staged[gbase[b] + (i - lo)]);
    }
}

// ---------------- place: per-bucket CSR finalize (XCD-local writes) ----------
__global__ __launch_bounds__(256) void place_edges(
    const int* __restrict__ bcnt, const int* __restrict__ staged,
    int* __restrict__ esrc, int* __restrict__ off, int* __restrict__ cnt,
    float* __restrict__ dinv, int n)
{
    __shared__ int cntL[256];
    __shared__ int scn[256];
    __shared__ int curL[256];
    int b = blockIdx.x;
    int tid = threadIdx.x;
    int node0 = b << 8;
    int nN = min(256, n - node0);
    int beg = b * CAP;
    int end = beg + bcnt[b];

    cntL[tid] = 0;
    __syncthreads();
    for (int i = beg + tid; i < end; i += 256)
        atomicAdd(&cntL[((unsigned)staged[i]) >> 24], 1);
    __syncthreads();
    scn[tid] = cntL[tid];
    __syncthreads();
    for (int d = 1; d < 256; d <<= 1) {
        int x = (tid >= d) ? scn[tid - d] : 0;
        __syncthreads();
        scn[tid] += x;
        __syncthreads();
    }
    int lofs = (tid == 0) ? 0 : scn[tid - 1];
    if (tid < nN) {
        int node = node0 + tid;
        off[node] = beg + lofs;
        cnt[node] = cntL[tid];
        dinv[node] = rsqrtf((float)cntL[tid] + 1.0f);
    }
    curL[tid] = beg + lofs;
    __syncthreads();
    for (int i = beg + tid; i < end; i += 256) {
        int u = staged[i];
        int pos = atomicAdd(&curL[((unsigned)u) >> 24], 1);
        __builtin_nontemporal_store(u & 0x00FFFFFF, &esrc[pos]);
    }
}

// ---------------- W prep bodies ----------------
template<int K, int FOUT>
__device__ __forceinline__ void prep_body3(
    const float* __restrict__ W, unsigned short* __restrict__ blob, int t)
{
    constexpr int CT = FOUT / 16;
    int lane = t & 63;
    int ct   = (t >> 6) % CT;
    int ks   = (t >> 6) / CT;
    int col  = ct * 16 + (lane & 15);
    int k0   = ks * 32 + (lane >> 4) * 8;

    union { bf16x8 v; unsigned short e[8]; } u;
#pragma unroll
    for (int j = 0; j < 8; ++j) {
        int kp = k0 + j;
        unsigned short r;
        if (kp < 2 * K) {
            int k = (kp < K) ? kp : kp - K;
            r = f2bf(W[k * FOUT + col]);
        } else {
            float f = W[(kp - 2 * K) * FOUT + col];
            unsigned short h = f2bf(f);
            r = f2bf(f - bf2f(h));
        }
        u.e[j] = r;
    }
    *reinterpret_cast<bf16x8*>(blob + (size_t)t * 8) = u.v;
}

template<int K, int FOUT>
__device__ __forceinline__ void prep_body2(
    const float* __restrict__ W, unsigned short* __restrict__ blob, int t)
{
    constexpr int CT = FOUT / 16;
    int lane = t & 63;
    int ct   = (t >> 6) % CT;
    int ks   = (t >> 6) / CT;
    int col  = ct * 16 + (lane & 15);
    int k0   = ks * 32 + (lane >> 4) * 8;

    union { bf16x8 v; unsigned short e[8]; } u;
#pragma unroll
    for (int j = 0; j < 8; ++j) {
        int kp = k0 + j;
        unsigned short r;
        if (kp < K) {
            r = f2bf(W[kp * FOUT + col]);
        } else {
            float f = W[(kp - K) * FOUT + col];
            unsigned short h = f2bf(f);
            r = f2bf(f - bf2f(h));
        }
        u.e[j] = r;
    }
    *reinterpret_cast<bf16x8*>(blob + (size_t)t * 8) = u.v;
}

__global__ __launch_bounds__(256) void prep_all(
    const float* __restrict__ W1, const float* __restrict__ W2,
    const float* __restrict__ W3, unsigned short* __restrict__ b1,
    unsigned short* __restrict__ b2, unsigned short* __restrict__ b3,
    int* __restrict__ bcur)
{
    int t = blockIdx.x * 256 + threadIdx.x;
    if (t < 3072)              prep_body3<128, 64>(W1, b1, t);
    else if (t < 3584)         prep_body2<64, 32>(W2, b2, t - 3072);
    else if (t < 3712)         prep_body2<32, 16>(W3, b3, t - 3584);
    else if (t < 3712 + K_BKT) bcur[t - 3712] = 0;
}

// ---------------- MFMA GEMM (f32 input, triple-K), 32-row tiles --------------
template<int K, int FOUT>
__global__ __launch_bounds__(256) void gemm_mfma(
    const float* __restrict__ h, const unsigned short* __restrict__ wtb,
    const float* __restrict__ dinv, unsigned short* __restrict__ hw, int n)
{
    constexpr int PAD = 8;
    constexpr int LDA = 2 * K + PAD;     // 264 -> 16.9 KB LDS
    constexpr int CT  = FOUT / 16;       // 4
    constexpr int KS  = (3 * K) / 32;    // 12
    __shared__ unsigned short As[32 * LDA];

    const int tid  = threadIdx.x;
    const int row0 = blockIdx.x * 32;

    constexpr int QK = K / 4;
    for (int i = tid; i < 32 * QK; i += 256) {
        int r = i / QK;
        int q = i % QK;
        int g = row0 + r;
        float4 v;
        if (g < n) v = *reinterpret_cast<const float4*>(h + (size_t)g * K + q * 4);
        else       v = make_float4(0.f, 0.f, 0.f, 0.f);
        ushort4 hi, lo;
        hi.x = f2bf(v.x); lo.x = f2bf(v.x - bf2f(hi.x));
        hi.y = f2bf(v.y); lo.y = f2bf(v.y - bf2f(hi.y));
        hi.z = f2bf(v.z); lo.z = f2bf(v.z - bf2f(hi.z));
        hi.w = f2bf(v.w); lo.w = f2bf(v.w - bf2f(hi.w));
        *reinterpret_cast<ushort4*>(&As[r * LDA + q * 4])     = hi;
        *reinterpret_cast<ushort4*>(&As[r * LDA + K + q * 4]) = lo;
    }
    __syncthreads();

    const int wave = tid >> 6;
    const int lane = tid & 63;
    const int l15  = lane & 15;
    const int kgrp = (lane >> 4) * 8;
    const int rw   = wave & 1;           // row half
    const int chf  = wave >> 1;          // col half
    const int arow = rw * 16 + l15;

    const unsigned short* wlane = wtb + lane * 8;

    f32x4 acc[2];
    acc[0] = (f32x4){0.f, 0.f, 0.f, 0.f};
    acc[1] = (f32x4){0.f, 0.f, 0.f, 0.f};

#pragma unroll
    for (int ks = 0; ks < KS; ++ks) {
        int kp = ks * 32 + kgrp;
        int ka = (kp >= 2 * K) ? kp - 2 * K : kp;
        bf16x8 a = *reinterpret_cast<const bf16x8*>(&As[arow * LDA + ka]);
#pragma unroll
        for (int hh = 0; hh < 2; ++hh) {
            int ct = chf * 2 + hh;
            bf16x8 b = *reinterpret_cast<const bf16x8*>(wlane + (ks * CT + ct) * 512);
            acc[hh] = __builtin_amdgcn_mfma_f32_16x16x32_bf16(a, b, acc[hh], 0, 0, 0);
        }
    }

    const int rbase = rw * 16 + (lane >> 4) * 4;
    float dv[4];
#pragma unroll
    for (int j = 0; j < 4; ++j) {
        int g = row0 + rbase + j;
        dv[j] = (g < n) ? dinv[g] : 0.f;
    }
#pragma unroll
    for (int hh = 0; hh < 2; ++hh) {
        int col = (chf * 2 + hh) * 16 + l15;
#pragma unroll
        for (int j = 0; j < 4; ++j) {
            int g = row0 + rbase + j;
            if (g < n) hw[(size_t)g * FOUT + col] = f2bf(acc[hh][j] * dv[j]);
        }
    }
}

// ---------------- fused: gather+BN+ReLU (64 nodes/block) -> LDS -> MFMA GEMM --
// Edge indices pulled into a 64-wide register window per node (one coalesced
// nt-load), distributed via __shfl; deg>64 handled by a fallback loop.
template<int F, int FOUT2>
__global__ __launch_bounds__(256) void gather_gemm(
    const int* __restrict__ off, const int* __restrict__ cnt,
    const int* __restrict__ esrc, const float* __restrict__ dinv,
    const unsigned short* __restrict__ hwin, const float* __restrict__ bias,
    const float* __restrict__ g, const float* __restrict__ be,
    const float* __restrict__ m, const float* __restrict__ v,
    const unsigned short* __restrict__ wtb, unsigned short* __restrict__ hwout,
    int n)
{
    constexpr int SG  = F / 4;
    constexpr int NSG = 64 / SG;
    constexpr int PAD = 8;
    constexpr int LDA = F + PAD;
    constexpr int CT  = FOUT2 / 16;
    constexpr int KS  = (2 * F) / 32;
    __shared__ unsigned short As[64 * LDA];

    const int tid   = threadIdx.x;
    const int wv    = tid >> 6;
    const int lane  = tid & 63;
    const int node0 = blockIdx.x * 64;
    const int sg = lane / SG;
    const int p  = lane % SG;

    // lane-parallel prefetch of off/cnt/dinv for the wave's 16 nodes
    int offv = 0, cntv = 0;
    float dnv = 0.f;
    {
        int nd = node0 + wv * 16 + (lane & 15);
        if (nd < n) {
            offv = off[nd];
            cntv = cnt[nd];
            dnv  = dinv[nd];
        }
    }

    for (int t = 0; t < 16; ++t) {
        int node = node0 + wv * 16 + t;
        int r = wv * 16 + t;
        int beg = __shfl(offv, t);
        int num = __shfl(cntv, t);
        float dn = __shfl(dnv, t);
        float sx = 0.f, sy = 0.f, sz = 0.f, sw = 0.f;
        if (node < n) {
            int eidx = 0;
            if (lane < num) eidx = __builtin_nontemporal_load(esrc + beg + lane);
            int lim = (num < 64) ? num : 64;
            int j = sg;
            for (; j + NSG < lim; j += 2 * NSG) {
                int s0 = __shfl(eidx, j);
                int s1 = __shfl(eidx, j + NSG);
                ushort4 a = *reinterpret_cast<const ushort4*>(hwin + (size_t)s0 * F + 4 * p);
                ushort4 b = *reinterpret_cast<const ushort4*>(hwin + (size_t)s1 * F + 4 * p);
                sx += bf2f(a.x) + bf2f(b.x);
                sy += bf2f(a.y) + bf2f(b.y);
                sz += bf2f(a.z) + bf2f(b.z);
                sw += bf2f(a.w) + bf2f(b.w);
            }
            if (j < lim) {
                int s0 = __shfl(eidx, j);
                ushort4 a = *reinterpret_cast<const ushort4*>(hwin + (size_t)s0 * F + 4 * p);
                sx += bf2f(a.x); sy += bf2f(a.y); sz += bf2f(a.z); sw += bf2f(a.w);
            }
            for (int jj = 64 + sg; jj < num; jj += NSG) {   // rare deg>64 tail
                int s0 = esrc[beg + jj];
                ushort4 a = *reinterpret_cast<const ushort4*>(hwin + (size_t)s0 * F + 4 * p);
                sx += bf2f(a.x); sy += bf2f(a.y); sz += bf2f(a.z); sw += bf2f(a.w);
            }
            if (sg == 0) {   // self-loop (hwin prescaled by dinv)
                ushort4 a = *reinterpret_cast<const ushort4*>(hwin + (size_t)node * F + 4 * p);
                sx += bf2f(a.x); sy += bf2f(a.y); sz += bf2f(a.z); sw += bf2f(a.w);
            }
        }
#pragma unroll
        for (int d = SG; d < 64; d <<= 1) {
            sx += __shfl_xor(sx, d);
            sy += __shfl_xor(sy, d);
            sz += __shfl_xor(sz, d);
            sw += __shfl_xor(sw, d);
        }
        if (sg == 0) {
            float y0 = 0.f, y1 = 0.f, y2 = 0.f, y3 = 0.f;
            int c0 = 4 * p;
            if (node < n) {
                float4 gg = *reinterpret_cast<const float4*>(g + c0);
                float4 vv = *reinterpret_cast<const float4*>(v + c0);
                float4 bb = *reinterpret_cast<const float4*>(bias + c0);
                float4 mm = *reinterpret_cast<const float4*>(m + c0);
                float4 ee = *reinterpret_cast<const float4*>(be + c0);
                y0 = fmaxf(gg.x * rsqrtf(vv.x + BN_EPS) * (dn * sx + bb.x - mm.x) + ee.x, 0.f);
                y1 = fmaxf(gg.y * rsqrtf(vv.y + BN_EPS) * (dn * sy + bb.y - mm.y) + ee.y, 0.f);
                y2 = fmaxf(gg.z * rsqrtf(vv.z + BN_EPS) * (dn * sz + bb.z - mm.z) + ee.z, 0.f);
                y3 = fmaxf(gg.w * rsqrtf(vv.w + BN_EPS) * (dn * sw + bb.w - mm.w) + ee.w, 0.f);
            }
            ushort4 pk;
            pk.x = f2bf(y0); pk.y = f2bf(y1); pk.z = f2bf(y2); pk.w = f2bf(y3);
            *reinterpret_cast<ushort4*>(&As[r * LDA + c0]) = pk;
        }
    }
    __syncthreads();

    // ---- GEMM phase: As(64 x F bf16) @ W -> hwout, prescaled by dinv ----
    const int l15  = lane & 15;
    const int kgrp = (lane >> 4) * 8;
    const int arow = wv * 16 + l15;
    const unsigned short* wlane = wtb + lane * 8;

    f32x4 acc[CT];
#pragma unroll
    for (int ct = 0; ct < CT; ++ct) acc[ct] = (f32x4){0.f, 0.f, 0.f, 0.f};

#pragma unroll
    for (int ks = 0; ks < KS; ++ks) {
        int kp = ks * 32 + kgrp;
        int ka = (kp >= F) ? kp - F : kp;
        bf16x8 a = *reinterpret_cast<const bf16x8*>(&As[arow * LDA + ka]);
#pragma unroll
        for (int ct = 0; ct < CT; ++ct) {
            bf16x8 b = *reinterpret_cast<const bf16x8*>(wlane + (ks * CT + ct) * 512);
            acc[ct] = __builtin_amdgcn_mfma_f32_16x16x32_bf16(a, b, acc[ct], 0, 0, 0);
        }
    }

    const int rbase = wv * 16 + (lane >> 4) * 4;
    float dv[4];
#pragma unroll
    for (int j = 0; j < 4; ++j) {
        int gr = node0 + rbase + j;
        dv[j] = (gr < n) ? dinv[gr] : 0.f;
    }
#pragma unroll
    for (int ct = 0; ct < CT; ++ct) {
#pragma unroll
        for (int j = 0; j < 4; ++j) {
            int gr = node0 + rbase + j;
            if (gr < n) hwout[(size_t)gr * FOUT2 + ct * 16 + l15] = f2bf(acc[ct][j] * dv[j]);
        }
    }
}

// ---------------- layer-3 gather fused with FC(16->8)+sigmoid ----------------
__global__ __launch_bounds__(256) void gather_bn_relu_fc(
    const int* __restrict__ off, const int* __restrict__ cnt,
    const int* __restrict__ esrc, const float* __restrict__ dinv,
    const unsigned short* __restrict__ hw, const float* __restrict__ bias,
    const float* __restrict__ g, const float* __restrict__ be,
    const float* __restrict__ m, const float* __restrict__ v,
    const float* __restrict__ fcW, const float* __restrict__ fcb,
    float* __restrict__ out, int n)
{
    constexpr int F = 16, SG = 4, NSG = 16;
    __shared__ float WsF[128];
    __shared__ float bsF[8];
    __shared__ float ybuf[4][16];

    int tid = threadIdx.x;
    if (tid < 128) WsF[tid] = fcW[tid];
    if (tid < 8)   bsF[tid] = fcb[tid];
    __syncthreads();

    int node = (blockIdx.x * 256 + tid) >> 6;
    int wv   = tid >> 6;
    int lane = tid & 63;
    bool act = node < n;

    if (act) {
        int sg = lane / SG;
        int p  = lane % SG;
        int beg = off[node];
        int num = cnt[node];

        float sx = 0.f, sy = 0.f, sz = 0.f, sw = 0.f;
        int eidx = 0;
        if (lane < num) eidx = __builtin_nontemporal_load(esrc + beg + lane);
        int lim = (num < 64) ? num : 64;
        int j = sg;
        for (; j + NSG < lim; j += 2 * NSG) {
            int s0 = __shfl(eidx, j);
            int s1 = __shfl(eidx, j + NSG);
            ushort4 a = *reinterpret_cast<const ushort4*>(hw + (size_t)s0 * F + 4 * p);
            ushort4 b = *reinterpret_cast<const ushort4*>(hw + (size_t)s1 * F + 4 * p);
            sx += bf2f(a.x) + bf2f(b.x);
            sy += bf2f(a.y) + bf2f(b.y);
            sz += bf2f(a.z) + bf2f(b.z);
            sw += bf2f(a.w) + bf2f(b.w);
        }
        if (j < lim) {
            int s0 = __shfl(eidx, j);
            ushort4 a = *reinterpret_cast<const ushort4*>(hw + (size_t)s0 * F + 4 * p);
            sx += bf2f(a.x); sy += bf2f(a.y); sz += bf2f(a.z); sw += bf2f(a.w);
        }
        for (int jj = 64 + sg; jj < num; jj += NSG) {   // rare deg>64 tail
            int s0 = esrc[beg + jj];
            ushort4 a = *reinterpret_cast<const ushort4*>(hw + (size_t)s0 * F + 4 * p);
            sx += bf2f(a.x); sy += bf2f(a.y); sz += bf2f(a.z); sw += bf2f(a.w);
        }
        if (sg == 0) {
            ushort4 a = *reinterpret_cast<const ushort4*>(hw + (size_t)node * F + 4 * p);
            sx += bf2f(a.x); sy += bf2f(a.y); sz += bf2f(a.z); sw += bf2f(a.w);
        }

#pragma unroll
        for (int d = SG; d < 64; d <<= 1) {
            sx += __shfl_xor(sx, d);
            sy += __shfl_xor(sy, d);
            sz += __shfl_xor(sz, d);
            sw += __shfl_xor(sw, d);
        }

        if (sg == 0) {
            int c0 = 4 * p;
            float dn = dinv[node];
            ybuf[wv][c0+0] = fmaxf(g[c0+0] * rsqrtf(v[c0+0] + BN_EPS) * (dn * sx + bias[c0+0] - m[c0+0]) + be[c0+0], 0.f);
            ybuf[wv][c0+1] = fmaxf(g[c0+1] * rsqrtf(v[c0+1] + BN_EPS) * (dn * sy + bias[c0+1] - m[c0+1]) + be[c0+1], 0.f);
            ybuf[wv][c0+2] = fmaxf(g[c0+2] * rsqrtf(v[c0+2] + BN_EPS) * (dn * sz + bias[c0+2] - m[c0+2]) + be[c0+2], 0.f);
            ybuf[wv][c0+3] = fmaxf(g[c0+3] * rsqrtf(v[c0+3] + BN_EPS) * (dn * sw + bias[c0+3] - m[c0+3]) + be[c0+3], 0.f);
        }
    }
    __syncthreads();

    if (act && lane < 8) {
        float o = bsF[lane];
#pragma unroll
        for (int k = 0; k < 16; ++k) o += ybuf[wv][k] * WsF[k * 8 + lane];
        out[(size_t)node * 8 + lane] = 1.0f / (1.0f + expf(-o));
    }
}

// ---------------- launch ----------------
extern "C" void kernel_launch(void* const* d_in, const int* in_sizes, int n_in,
                              void* d_out, int out_size, void* d_ws, size_t ws_size,
                              hipStream_t stream) {
    const float* x   = (const float*)d_in[0];
    const int*   ei  = (const int*)  d_in[1];   // [2, E]: src row then dst row
    const float* W1  = (const float*)d_in[2];
    const float* b1  = (const float*)d_in[3];
    const float* g1  = (const float*)d_in[4];
    const float* be1 = (const float*)d_in[5];
    const float* m1  = (const float*)d_in[6];
    const float* v1  = (const float*)d_in[7];
    const float* W2  = (const float*)d_in[8];
    const float* b2  = (const float*)d_in[9];
    const float* g2  = (const float*)d_in[10];
    const float* be2 = (const float*)d_in[11];
    const float* m2  = (const float*)d_in[12];
    const float* v2  = (const float*)d_in[13];
    const float* W3  = (const float*)d_in[14];
    const float* b3  = (const float*)d_in[15];
    const float* g3  = (const float*)d_in[16];
    const float* be3 = (const float*)d_in[17];
    const float* m3  = (const float*)d_in[18];
    const float* v3  = (const float*)d_in[19];
    const float* fcW = (const float*)d_in[20];
    const float* fcb = (const float*)d_in[21];
    float* out = (float*)d_out;

    const int* src = ei;
    const int* dst = ei + NE;

    char* w = (char*)d_ws;
    float* dinv  = (float*)(w + 0);                   // N f32
    int*   cnt   = (int*)  (w + (512 << 10));         // N i32
    int*   off   = (int*)  (w + (1024 << 10));        // N i32
    int*   bcur  = (int*)  (w + (1536 << 10));        // K_BKT i32
    int*   staged= (int*)  (w + (2u << 20));          // K_BKT*CAP i32 = 9.6 MB
    int*   esrc  = (int*)  (w + (12u << 20));         // K_BKT*CAP i32 = 9.6 MB
    unsigned short* wt1 = (unsigned short*)(w + (22u << 20)); // 48 KB blob (triple-K)
    unsigned short* wt2 = wt1 + 24576;                         // 8 KB blob (double-K)
    unsigned short* wt3 = wt2 + 4096;                          // 2 KB blob (double-K)
    unsigned short* hw1 = (unsigned short*)(w + (24u << 20)); // N*64 bf16 = 12.8 MB
    unsigned short* hw2 = (unsigned short*)(w + (38u << 20)); // N*32 bf16 = 6.4 MB
    unsigned short* hw3 = (unsigned short*)(w + (46u << 20)); // N*16 bf16 = 3.2 MB

    // ---- W blobs + bcur zero (one kernel) ----
    prep_all<<<(3712 + K_BKT + 255) / 256, 256, 0, stream>>>(
        W1, W2, W3, wt1, wt2, wt3, bcur);

    // ---- CSR build: partition (fixed-capacity buckets) -> place ----
    partition_edges<<<(NE + CH - 1) / CH, 256, 0, stream>>>(src, dst, bcur, staged, NE);
    place_edges<<<K_BKT, 256, 0, stream>>>(bcur, staged, esrc, off, cnt, dinv, NN);

    const int GB = (NN + 63) / 64;          // 64 nodes per block (gather_gemm)
    const int GG = (NN * 64 + 255) / 256;   // one wave per node (layer-3)

    // layer 1 transform (MFMA, f32 in, triple-K, 32-row tiles)
    gemm_mfma<128, 64><<<(NN + 31) / 32, 256, 0, stream>>>(x, wt1, dinv, hw1, NN);

    // layer 1 gather + BN + ReLU -> LDS -> MFMA (h1 @ W2) -> hw2
    gather_gemm<64, 32><<<GB, 256, 0, stream>>>(
        off, cnt, esrc, dinv, hw1, b1, g1, be1, m1, v1, wt2, hw2, NN);

    // layer 2 gather + BN + ReLU -> LDS -> MFMA (h2 @ W3) -> hw3
    gather_gemm<32, 16><<<GB, 256, 0, stream>>>(
        off, cnt, esrc, dinv, hw2, b2, g2, be2, m2, v2, wt3, hw3, NN);

    // layer 3 gather fused with FC + sigmoid
    gather_bn_relu_fc<<<GG, 256, 0, stream>>>(
        off, cnt, esrc, dinv, hw3, b3, g3, be3, m3, v3, fcW, fcb, out, NN);
}

// Round 16
// 233.936 us; speedup vs baseline: 1.2939x; 1.2939x over previous
//
#include <hip/hip_runtime.h>
#include <math.h>

static constexpr int NN = 100000;   // nodes
static constexpr int NE = 1600000;  // edges
static constexpr float BN_EPS = 1e-5f;
static constexpr int K_BKT = (NN + 255) / 256;   // 391 coarse buckets (dst>>8)
static constexpr int CH = 4096;                  // edges per partition block
static constexpr int CAP = 6144;                 // fixed slots per bucket (mean 4096)

typedef __attribute__((ext_vector_type(8))) short bf16x8;
typedef __attribute__((ext_vector_type(4))) float f32x4;

// bf16 helpers (RNE pack, exact unpack)
__device__ __forceinline__ unsigned short f2bf(float f) {
    unsigned int u = __float_as_uint(f);
    u += 0x7fffu + ((u >> 16) & 1u);
    return (unsigned short)(u >> 16);
}
__device__ __forceinline__ float bf2f(unsigned short b) {
    return __uint_as_float(((unsigned int)b) << 16);
}

// ---------------- partition: bucket-grouped staged writes, fixed-capacity ----
__global__ __launch_bounds__(256) void partition_edges(
    const int* __restrict__ src, const int* __restrict__ dst,
    int* __restrict__ bcur, int* __restrict__ staged, int e)
{
    __shared__ int s_out[CH];       // 16 KB
    __shared__ int cntL[512];       // counts -> inclusive scan
    __shared__ int gbase[K_BKT];
    __shared__ int curL[K_BKT];

    int tid = threadIdx.x;
    int c0 = blockIdx.x * CH;
    int cend = min(c0 + CH, e);

    for (int i = tid; i < 512; i += 256) cntL[i] = 0;
    __syncthreads();

    int sreg[16], dreg[16];
#pragma unroll
    for (int k = 0; k < 16; ++k) {
        int i = c0 + tid + k * 256;
        if (i < cend) {
            sreg[k] = src[i];
            dreg[k] = dst[i];
            atomicAdd(&cntL[((unsigned)dreg[k]) >> 8], 1);
        }
    }
    __syncthreads();

    for (int b = tid; b < K_BKT; b += 256) {
        int c = cntL[b];
        gbase[b] = (c > 0) ? (b * CAP + atomicAdd(&bcur[b], c)) : 0;
    }
    __syncthreads();

    for (int d = 1; d < 512; d <<= 1) {
        int x0 = (tid >= d) ? cntL[tid - d] : 0;
        int i1 = tid + 256;
        int x1 = (i1 >= d) ? cntL[i1 - d] : 0;
        __syncthreads();
        cntL[tid] += x0;
        cntL[i1]  += x1;
        __syncthreads();
    }
    for (int b = tid; b < K_BKT; b += 256)
        curL[b] = (b == 0) ? 0 : cntL[b - 1];
    __syncthreads();

#pragma unroll
    for (int k = 0; k < 16; ++k) {
        int i = c0 + tid + k * 256;
        if (i < cend) {
            int b = ((unsigned)dreg[k]) >> 8;
            int r = atomicAdd(&curL[b], 1);
            s_out[r] = sreg[k] | ((dreg[k] & 255) << 24);
        }
    }
    __syncthreads();

    int wave = tid >> 6, lane = tid & 63;
    for (int b = wave; b < K_BKT; b += 4) {
        int lo = (b == 0) ? 0 : cntL[b - 1];
        int hi = cntL[b];
        int gb = gbase[b];
        for (int i = lo + lane; i < hi; i += 64)
            staged[gb + (i - lo)] = s_out[i];
    }
}

// ---------------- place: per-bucket CSR finalize (XCD-local writes) ----------
__global__ __launch_bounds__(256) void place_edges(
    const int* __restrict__ bcnt, const int* __restrict__ staged,
    int* __restrict__ esrc, int* __restrict__ off, int* __restrict__ cnt,
    float* __restrict__ dinv, int n)
{
    __shared__ int cntL[256];
    __shared__ int scn[256];
    __shared__ int curL[256];
    int b = blockIdx.x;
    int tid = threadIdx.x;
    int node0 = b << 8;
    int nN = min(256, n - node0);
    int beg = b * CAP;
    int end = beg + bcnt[b];

    cntL[tid] = 0;
    __syncthreads();
    for (int i = beg + tid; i < end; i += 256)
        atomicAdd(&cntL[((unsigned)staged[i]) >> 24], 1);
    __syncthreads();
    scn[tid] = cntL[tid];
    __syncthreads();
    for (int d = 1; d < 256; d <<= 1) {
        int x = (tid >= d) ? scn[tid - d] : 0;
        __syncthreads();
        scn[tid] += x;
        __syncthreads();
    }
    int lofs = (tid == 0) ? 0 : scn[tid - 1];
    if (tid < nN) {
        int node = node0 + tid;
        off[node] = beg + lofs;
        cnt[node] = cntL[tid];
        dinv[node] = rsqrtf((float)cntL[tid] + 1.0f);
    }
    curL[tid] = beg + lofs;
    __syncthreads();
    for (int i = beg + tid; i < end; i += 256) {
        int u = staged[i];
        int pos = atomicAdd(&curL[((unsigned)u) >> 24], 1);
        esrc[pos] = u & 0x00FFFFFF;
    }
}

// ---------------- W prep bodies ----------------
template<int K, int FOUT>
__device__ __forceinline__ void prep_body3(
    const float* __restrict__ W, unsigned short* __restrict__ blob, int t)
{
    constexpr int CT = FOUT / 16;
    int lane = t & 63;
    int ct   = (t >> 6) % CT;
    int ks   = (t >> 6) / CT;
    int col  = ct * 16 + (lane & 15);
    int k0   = ks * 32 + (lane >> 4) * 8;

    union { bf16x8 v; unsigned short e[8]; } u;
#pragma unroll
    for (int j = 0; j < 8; ++j) {
        int kp = k0 + j;
        unsigned short r;
        if (kp < 2 * K) {
            int k = (kp < K) ? kp : kp - K;
            r = f2bf(W[k * FOUT + col]);
        } else {
            float f = W[(kp - 2 * K) * FOUT + col];
            unsigned short h = f2bf(f);
            r = f2bf(f - bf2f(h));
        }
        u.e[j] = r;
    }
    *reinterpret_cast<bf16x8*>(blob + (size_t)t * 8) = u.v;
}

template<int K, int FOUT>
__device__ __forceinline__ void prep_body2(
    const float* __restrict__ W, unsigned short* __restrict__ blob, int t)
{
    constexpr int CT = FOUT / 16;
    int lane = t & 63;
    int ct   = (t >> 6) % CT;
    int ks   = (t >> 6) / CT;
    int col  = ct * 16 + (lane & 15);
    int k0   = ks * 32 + (lane >> 4) * 8;

    union { bf16x8 v; unsigned short e[8]; } u;
#pragma unroll
    for (int j = 0; j < 8; ++j) {
        int kp = k0 + j;
        unsigned short r;
        if (kp < K) {
            r = f2bf(W[kp * FOUT + col]);
        } else {
            float f = W[(kp - K) * FOUT + col];
            unsigned short h = f2bf(f);
            r = f2bf(f - bf2f(h));
        }
        u.e[j] = r;
    }
    *reinterpret_cast<bf16x8*>(blob + (size_t)t * 8) = u.v;
}

__global__ __launch_bounds__(256) void prep_all(
    const float* __restrict__ W1, const float* __restrict__ W2,
    const float* __restrict__ W3, unsigned short* __restrict__ b1,
    unsigned short* __restrict__ b2, unsigned short* __restrict__ b3,
    int* __restrict__ bcur)
{
    int t = blockIdx.x * 256 + threadIdx.x;
    if (t < 3072)              prep_body3<128, 64>(W1, b1, t);
    else if (t < 3584)         prep_body2<64, 32>(W2, b2, t - 3072);
    else if (t < 3712)         prep_body2<32, 16>(W3, b3, t - 3584);
    else if (t < 3712 + K_BKT) bcur[t - 3712] = 0;
}

// ---------------- MFMA GEMM (f32 input, triple-K), 32-row tiles --------------
// wave w: row-half (w&1), col-half (w>>1) -> 2 col-tiles of 16.
template<int K, int FOUT>
__global__ __launch_bounds__(256) void gemm_mfma(
    const float* __restrict__ h, const unsigned short* __restrict__ wtb,
    const float* __restrict__ dinv, unsigned short* __restrict__ hw, int n)
{
    constexpr int PAD = 8;
    constexpr int LDA = 2 * K + PAD;     // 264 -> 16.9 KB LDS
    constexpr int CT  = FOUT / 16;       // 4
    constexpr int KS  = (3 * K) / 32;    // 12
    __shared__ unsigned short As[32 * LDA];

    const int tid  = threadIdx.x;
    const int row0 = blockIdx.x * 32;

    constexpr int QK = K / 4;
    for (int i = tid; i < 32 * QK; i += 256) {
        int r = i / QK;
        int q = i % QK;
        int g = row0 + r;
        float4 v;
        if (g < n) v = *reinterpret_cast<const float4*>(h + (size_t)g * K + q * 4);
        else       v = make_float4(0.f, 0.f, 0.f, 0.f);
        ushort4 hi, lo;
        hi.x = f2bf(v.x); lo.x = f2bf(v.x - bf2f(hi.x));
        hi.y = f2bf(v.y); lo.y = f2bf(v.y - bf2f(hi.y));
        hi.z = f2bf(v.z); lo.z = f2bf(v.z - bf2f(hi.z));
        hi.w = f2bf(v.w); lo.w = f2bf(v.w - bf2f(hi.w));
        *reinterpret_cast<ushort4*>(&As[r * LDA + q * 4])     = hi;
        *reinterpret_cast<ushort4*>(&As[r * LDA + K + q * 4]) = lo;
    }
    __syncthreads();

    const int wave = tid >> 6;
    const int lane = tid & 63;
    const int l15  = lane & 15;
    const int kgrp = (lane >> 4) * 8;
    const int rw   = wave & 1;           // row half
    const int chf  = wave >> 1;          // col half
    const int arow = rw * 16 + l15;

    const unsigned short* wlane = wtb + lane * 8;

    f32x4 acc[2];
    acc[0] = (f32x4){0.f, 0.f, 0.f, 0.f};
    acc[1] = (f32x4){0.f, 0.f, 0.f, 0.f};

#pragma unroll
    for (int ks = 0; ks < KS; ++ks) {
        int kp = ks * 32 + kgrp;
        int ka = (kp >= 2 * K) ? kp - 2 * K : kp;
        bf16x8 a = *reinterpret_cast<const bf16x8*>(&As[arow * LDA + ka]);
#pragma unroll
        for (int hh = 0; hh < 2; ++hh) {
            int ct = chf * 2 + hh;
            bf16x8 b = *reinterpret_cast<const bf16x8*>(wlane + (ks * CT + ct) * 512);
            acc[hh] = __builtin_amdgcn_mfma_f32_16x16x32_bf16(a, b, acc[hh], 0, 0, 0);
        }
    }

    const int rbase = rw * 16 + (lane >> 4) * 4;
    float dv[4];
#pragma unroll
    for (int j = 0; j < 4; ++j) {
        int g = row0 + rbase + j;
        dv[j] = (g < n) ? dinv[g] : 0.f;
    }
#pragma unroll
    for (int hh = 0; hh < 2; ++hh) {
        int col = (chf * 2 + hh) * 16 + l15;
#pragma unroll
        for (int j = 0; j < 4; ++j) {
            int g = row0 + rbase + j;
            if (g < n) hw[(size_t)g * FOUT + col] = f2bf(acc[hh][j] * dv[j]);
        }
    }
}

// ---------------- fused: gather+BN+ReLU (64 nodes/block) -> LDS -> MFMA GEMM --
template<int F, int FOUT2>
__global__ __launch_bounds__(256) void gather_gemm(
    const int* __restrict__ off, const int* __restrict__ cnt,
    const int* __restrict__ esrc, const float* __restrict__ dinv,
    const unsigned short* __restrict__ hwin, const float* __restrict__ bias,
    const float* __restrict__ g, const float* __restrict__ be,
    const float* __restrict__ m, const float* __restrict__ v,
    const unsigned short* __restrict__ wtb, unsigned short* __restrict__ hwout,
    int n)
{
    constexpr int SG  = F / 4;
    constexpr int NSG = 64 / SG;
    constexpr int PAD = 8;
    constexpr int LDA = F + PAD;
    constexpr int CT  = FOUT2 / 16;
    constexpr int KS  = (2 * F) / 32;
    __shared__ unsigned short As[64 * LDA];

    const int tid   = threadIdx.x;
    const int wv    = tid >> 6;
    const int lane  = tid & 63;
    const int node0 = blockIdx.x * 64;
    const int sg = lane / SG;
    const int p  = lane % SG;

    // lane-parallel prefetch of off/cnt/dinv for the wave's 16 nodes
    int offv = 0, cntv = 0;
    float dnv = 0.f;
    {
        int nd = node0 + wv * 16 + (lane & 15);
        if (nd < n) {
            offv = off[nd];
            cntv = cnt[nd];
            dnv  = dinv[nd];
        }
    }

    for (int t = 0; t < 16; ++t) {
        int node = node0 + wv * 16 + t;
        int r = wv * 16 + t;
        int beg = __shfl(offv, t);
        int num = __shfl(cntv, t);
        float dn = __shfl(dnv, t);
        float sx = 0.f, sy = 0.f, sz = 0.f, sw = 0.f;
        if (node < n) {
            int j = sg;
            for (; j + NSG < num; j += 2 * NSG) {
                int s0 = esrc[beg + j];
                int s1 = esrc[beg + j + NSG];
                ushort4 a = *reinterpret_cast<const ushort4*>(hwin + (size_t)s0 * F + 4 * p);
                ushort4 b = *reinterpret_cast<const ushort4*>(hwin + (size_t)s1 * F + 4 * p);
                sx += bf2f(a.x) + bf2f(b.x);
                sy += bf2f(a.y) + bf2f(b.y);
                sz += bf2f(a.z) + bf2f(b.z);
                sw += bf2f(a.w) + bf2f(b.w);
            }
            if (j < num) {
                int s0 = esrc[beg + j];
                ushort4 a = *reinterpret_cast<const ushort4*>(hwin + (size_t)s0 * F + 4 * p);
                sx += bf2f(a.x); sy += bf2f(a.y); sz += bf2f(a.z); sw += bf2f(a.w);
            }
            if (sg == 0) {   // self-loop (hwin prescaled by dinv)
                ushort4 a = *reinterpret_cast<const ushort4*>(hwin + (size_t)node * F + 4 * p);
                sx += bf2f(a.x); sy += bf2f(a.y); sz += bf2f(a.z); sw += bf2f(a.w);
            }
        }
#pragma unroll
        for (int d = SG; d < 64; d <<= 1) {
            sx += __shfl_xor(sx, d);
            sy += __shfl_xor(sy, d);
            sz += __shfl_xor(sz, d);
            sw += __shfl_xor(sw, d);
        }
        if (sg == 0) {
            float y0 = 0.f, y1 = 0.f, y2 = 0.f, y3 = 0.f;
            int c0 = 4 * p;
            if (node < n) {
                float4 gg = *reinterpret_cast<const float4*>(g + c0);
                float4 vv = *reinterpret_cast<const float4*>(v + c0);
                float4 bb = *reinterpret_cast<const float4*>(bias + c0);
                float4 mm = *reinterpret_cast<const float4*>(m + c0);
                float4 ee = *reinterpret_cast<const float4*>(be + c0);
                y0 = fmaxf(gg.x * rsqrtf(vv.x + BN_EPS) * (dn * sx + bb.x - mm.x) + ee.x, 0.f);
                y1 = fmaxf(gg.y * rsqrtf(vv.y + BN_EPS) * (dn * sy + bb.y - mm.y) + ee.y, 0.f);
                y2 = fmaxf(gg.z * rsqrtf(vv.z + BN_EPS) * (dn * sz + bb.z - mm.z) + ee.z, 0.f);
                y3 = fmaxf(gg.w * rsqrtf(vv.w + BN_EPS) * (dn * sw + bb.w - mm.w) + ee.w, 0.f);
            }
            ushort4 pk;
            pk.x = f2bf(y0); pk.y = f2bf(y1); pk.z = f2bf(y2); pk.w = f2bf(y3);
            *reinterpret_cast<ushort4*>(&As[r * LDA + c0]) = pk;
        }
    }
    __syncthreads();

    // ---- GEMM phase: As(64 x F bf16) @ W -> hwout, prescaled by dinv ----
    const int l15  = lane & 15;
    const int kgrp = (lane >> 4) * 8;
    const int arow = wv * 16 + l15;
    const unsigned short* wlane = wtb + lane * 8;

    f32x4 acc[CT];
#pragma unroll
    for (int ct = 0; ct < CT; ++ct) acc[ct] = (f32x4){0.f, 0.f, 0.f, 0.f};

#pragma unroll
    for (int ks = 0; ks < KS; ++ks) {
        int kp = ks * 32 + kgrp;
        int ka = (kp >= F) ? kp - F : kp;
        bf16x8 a = *reinterpret_cast<const bf16x8*>(&As[arow * LDA + ka]);
#pragma unroll
        for (int ct = 0; ct < CT; ++ct) {
            bf16x8 b = *reinterpret_cast<const bf16x8*>(wlane + (ks * CT + ct) * 512);
            acc[ct] = __builtin_amdgcn_mfma_f32_16x16x32_bf16(a, b, acc[ct], 0, 0, 0);
        }
    }

    const int rbase = wv * 16 + (lane >> 4) * 4;
    float dv[4];
#pragma unroll
    for (int j = 0; j < 4; ++j) {
        int gr = node0 + rbase + j;
        dv[j] = (gr < n) ? dinv[gr] : 0.f;
    }
#pragma unroll
    for (int ct = 0; ct < CT; ++ct) {
#pragma unroll
        for (int j = 0; j < 4; ++j) {
            int gr = node0 + rbase + j;
            if (gr < n) hwout[(size_t)gr * FOUT2 + ct * 16 + l15] = f2bf(acc[ct][j] * dv[j]);
        }
    }
}

// ---------------- layer-3 gather fused with FC(16->8)+sigmoid ----------------
__global__ __launch_bounds__(256) void gather_bn_relu_fc(
    const int* __restrict__ off, const int* __restrict__ cnt,
    const int* __restrict__ esrc, const float* __restrict__ dinv,
    const unsigned short* __restrict__ hw, const float* __restrict__ bias,
    const float* __restrict__ g, const float* __restrict__ be,
    const float* __restrict__ m, const float* __restrict__ v,
    const float* __restrict__ fcW, const float* __restrict__ fcb,
    float* __restrict__ out, int n)
{
    constexpr int F = 16, SG = 4, NSG = 16;
    __shared__ float WsF[128];
    __shared__ float bsF[8];
    __shared__ float ybuf[4][16];

    int tid = threadIdx.x;
    if (tid < 128) WsF[tid] = fcW[tid];
    if (tid < 8)   bsF[tid] = fcb[tid];
    __syncthreads();

    int node = (blockIdx.x * 256 + tid) >> 6;
    int wv   = tid >> 6;
    int lane = tid & 63;
    bool act = node < n;

    if (act) {
        int sg = lane / SG;
        int p  = lane % SG;
        int beg = off[node];
        int num = cnt[node];

        float sx = 0.f, sy = 0.f, sz = 0.f, sw = 0.f;
        int j = sg;
        for (; j + NSG < num; j += 2 * NSG) {
            int s0 = esrc[beg + j];
            int s1 = esrc[beg + j + NSG];
            ushort4 a = *reinterpret_cast<const ushort4*>(hw + (size_t)s0 * F + 4 * p);
            ushort4 b = *reinterpret_cast<const ushort4*>(hw + (size_t)s1 * F + 4 * p);
            sx += bf2f(a.x) + bf2f(b.x);
            sy += bf2f(a.y) + bf2f(b.y);
            sz += bf2f(a.z) + bf2f(b.z);
            sw += bf2f(a.w) + bf2f(b.w);
        }
        if (j < num) {
            int s0 = esrc[beg + j];
            ushort4 a = *reinterpret_cast<const ushort4*>(hw + (size_t)s0 * F + 4 * p);
            sx += bf2f(a.x); sy += bf2f(a.y); sz += bf2f(a.z); sw += bf2f(a.w);
        }
        if (sg == 0) {
            ushort4 a = *reinterpret_cast<const ushort4*>(hw + (size_t)node * F + 4 * p);
            sx += bf2f(a.x); sy += bf2f(a.y); sz += bf2f(a.z); sw += bf2f(a.w);
        }

#pragma unroll
        for (int d = SG; d < 64; d <<= 1) {
            sx += __shfl_xor(sx, d);
            sy += __shfl_xor(sy, d);
            sz += __shfl_xor(sz, d);
            sw += __shfl_xor(sw, d);
        }

        if (sg == 0) {
            int c0 = 4 * p;
            float dn = dinv[node];
            ybuf[wv][c0+0] = fmaxf(g[c0+0] * rsqrtf(v[c0+0] + BN_EPS) * (dn * sx + bias[c0+0] - m[c0+0]) + be[c0+0], 0.f);
            ybuf[wv][c0+1] = fmaxf(g[c0+1] * rsqrtf(v[c0+1] + BN_EPS) * (dn * sy + bias[c0+1] - m[c0+1]) + be[c0+1], 0.f);
            ybuf[wv][c0+2] = fmaxf(g[c0+2] * rsqrtf(v[c0+2] + BN_EPS) * (dn * sz + bias[c0+2] - m[c0+2]) + be[c0+2], 0.f);
            ybuf[wv][c0+3] = fmaxf(g[c0+3] * rsqrtf(v[c0+3] + BN_EPS) * (dn * sw + bias[c0+3] - m[c0+3]) + be[c0+3], 0.f);
        }
    }
    __syncthreads();

    if (act && lane < 8) {
        float o = bsF[lane];
#pragma unroll
        for (int k = 0; k < 16; ++k) o += ybuf[wv][k] * WsF[k * 8 + lane];
        out[(size_t)node * 8 + lane] = 1.0f / (1.0f + expf(-o));
    }
}

// ---------------- launch ----------------
extern "C" void kernel_launch(void* const* d_in, const int* in_sizes, int n_in,
                              void* d_out, int out_size, void* d_ws, size_t ws_size,
                              hipStream_t stream) {
    const float* x   = (const float*)d_in[0];
    const int*   ei  = (const int*)  d_in[1];   // [2, E]: src row then dst row
    const float* W1  = (const float*)d_in[2];
    const float* b1  = (const float*)d_in[3];
    const float* g1  = (const float*)d_in[4];
    const float* be1 = (const float*)d_in[5];
    const float* m1  = (const float*)d_in[6];
    const float* v1  = (const float*)d_in[7];
    const float* W2  = (const float*)d_in[8];
    const float* b2  = (const float*)d_in[9];
    const float* g2  = (const float*)d_in[10];
    const float* be2 = (const float*)d_in[11];
    const float* m2  = (const float*)d_in[12];
    const float* v2  = (const float*)d_in[13];
    const float* W3  = (const float*)d_in[14];
    const float* b3  = (const float*)d_in[15];
    const float* g3  = (const float*)d_in[16];
    const float* be3 = (const float*)d_in[17];
    const float* m3  = (const float*)d_in[18];
    const float* v3  = (const float*)d_in[19];
    const float* fcW = (const float*)d_in[20];
    const float* fcb = (const float*)d_in[21];
    float* out = (float*)d_out;

    const int* src = ei;
    const int* dst = ei + NE;

    char* w = (char*)d_ws;
    float* dinv  = (float*)(w + 0);                   // N f32
    int*   cnt   = (int*)  (w + (512 << 10));         // N i32
    int*   off   = (int*)  (w + (1024 << 10));        // N i32
    int*   bcur  = (int*)  (w + (1536 << 10));        // K_BKT i32
    int*   staged= (int*)  (w + (2u << 20));          // K_BKT*CAP i32 = 9.6 MB
    int*   esrc  = (int*)  (w + (12u << 20));         // K_BKT*CAP i32 = 9.6 MB
    unsigned short* wt1 = (unsigned short*)(w + (22u << 20)); // 48 KB blob (triple-K)
    unsigned short* wt2 = wt1 + 24576;                         // 8 KB blob (double-K)
    unsigned short* wt3 = wt2 + 4096;                          // 2 KB blob (double-K)
    unsigned short* hw1 = (unsigned short*)(w + (24u << 20)); // N*64 bf16 = 12.8 MB
    unsigned short* hw2 = (unsigned short*)(w + (38u << 20)); // N*32 bf16 = 6.4 MB
    unsigned short* hw3 = (unsigned short*)(w + (46u << 20)); // N*16 bf16 = 3.2 MB

    // ---- W blobs + bcur zero (one kernel) ----
    prep_all<<<(3712 + K_BKT + 255) / 256, 256, 0, stream>>>(
        W1, W2, W3, wt1, wt2, wt3, bcur);

    // ---- CSR build: partition (fixed-capacity buckets) -> place ----
    partition_edges<<<(NE + CH - 1) / CH, 256, 0, stream>>>(src, dst, bcur, staged, NE);
    place_edges<<<K_BKT, 256, 0, stream>>>(bcur, staged, esrc, off, cnt, dinv, NN);

    const int GB = (NN + 63) / 64;          // 64 nodes per block (gather_gemm)
    const int GG = (NN * 64 + 255) / 256;   // one wave per node (layer-3)

    // layer 1 transform (MFMA, f32 in, triple-K, 32-row tiles)
    gemm_mfma<128, 64><<<(NN + 31) / 32, 256, 0, stream>>>(x, wt1, dinv, hw1, NN);

    // layer 1 gather + BN + ReLU -> LDS -> MFMA (h1 @ W2) -> hw2
    gather_gemm<64, 32><<<GB, 256, 0, stream>>>(
        off, cnt, esrc, dinv, hw1, b1, g1, be1, m1, v1, wt2, hw2, NN);

    // layer 2 gather + BN + ReLU -> LDS -> MFMA (h2 @ W3) -> hw3
    gather_gemm<32, 16><<<GB, 256, 0, stream>>>(
        off, cnt, esrc, dinv, hw2, b2, g2, be2, m2, v2, wt3, hw3, NN);

    // layer 3 gather fused with FC + sigmoid
    gather_bn_relu_fc<<<GG, 256, 0, stream>>>(
        off, cnt, esrc, dinv, hw3, b3, g3, be3, m3, v3, fcW, fcb, out, NN);
}

// Round 17
// 219.997 us; speedup vs baseline: 1.3759x; 1.0634x over previous
//
#include <hip/hip_runtime.h>
#include <math.h>

static constexpr int NN = 100000;   // nodes
static constexpr int NE = 1600000;  // edges
static constexpr float BN_EPS = 1e-5f;
static constexpr int K_BKT = (NN + 255) / 256;   // 391 coarse buckets (dst>>8)
static constexpr int CH = 4096;                  // edges per partition block
static constexpr int CAP = 6144;                 // fixed slots per bucket (mean 4096)

typedef __attribute__((ext_vector_type(8))) short bf16x8;
typedef __attribute__((ext_vector_type(4))) float f32x4;

// bf16 helpers (RNE pack, exact unpack)
__device__ __forceinline__ unsigned short f2bf(float f) {
    unsigned int u = __float_as_uint(f);
    u += 0x7fffu + ((u >> 16) & 1u);
    return (unsigned short)(u >> 16);
}
__device__ __forceinline__ float bf2f(unsigned short b) {
    return __uint_as_float(((unsigned int)b) << 16);
}

// ---------------- partition: bucket-grouped staged writes, fixed-capacity ----
// Write-out is a flat all-lane loop with branchless binary search over the
// scanned counts (runs are ~10 edges; per-bucket wave walk left 54/64 lanes idle).
__global__ __launch_bounds__(256) void partition_edges(
    const int* __restrict__ src, const int* __restrict__ dst,
    int* __restrict__ bcur, int* __restrict__ staged, int e)
{
    __shared__ int s_out[CH];       // 16 KB
    __shared__ int cntL[512];       // counts -> inclusive scan
    __shared__ int gbase[K_BKT];
    __shared__ int curL[K_BKT];

    int tid = threadIdx.x;
    int c0 = blockIdx.x * CH;
    int cend = min(c0 + CH, e);
    int nE = cend - c0;

    for (int i = tid; i < 512; i += 256) cntL[i] = 0;
    __syncthreads();

    int sreg[16], dreg[16];
#pragma unroll
    for (int k = 0; k < 16; ++k) {
        int i = c0 + tid + k * 256;
        if (i < cend) {
            sreg[k] = src[i];
            dreg[k] = dst[i];
            atomicAdd(&cntL[((unsigned)dreg[k]) >> 8], 1);
        }
    }
    __syncthreads();

    // reserve contiguous runs inside each bucket's fixed region
    for (int b = tid; b < K_BKT; b += 256) {
        int c = cntL[b];
        gbase[b] = (c > 0) ? (b * CAP + atomicAdd(&bcur[b], c)) : 0;
    }
    __syncthreads();

    // inclusive scan of cntL (512, 2 elems/thread Hillis-Steele)
    for (int d = 1; d < 512; d <<= 1) {
        int x0 = (tid >= d) ? cntL[tid - d] : 0;
        int i1 = tid + 256;
        int x1 = (i1 >= d) ? cntL[i1 - d] : 0;
        __syncthreads();
        cntL[tid] += x0;
        cntL[i1]  += x1;
        __syncthreads();
    }
    for (int b = tid; b < K_BKT; b += 256)
        curL[b] = (b == 0) ? 0 : cntL[b - 1];
    __syncthreads();

    // reorder into LDS grouped by bucket (registers, no re-read)
#pragma unroll
    for (int k = 0; k < 16; ++k) {
        int i = c0 + tid + k * 256;
        if (i < cend) {
            int b = ((unsigned)dreg[k]) >> 8;
            int r = atomicAdd(&curL[b], 1);
            s_out[r] = sreg[k] | ((dreg[k] & 255) << 24);
        }
    }
    __syncthreads();

    // flat write-out: element i -> bucket via binary search on scanned cntL
    for (int i = tid; i < nE; i += 256) {
        int val = s_out[i];
        int b = 0;
#pragma unroll
        for (int step = 256; step >= 1; step >>= 1) {
            int nb = b + step;
            if (nb <= 512 && cntL[nb - 1] <= i) b = nb;
        }
        int lo = (b == 0) ? 0 : cntL[b - 1];
        staged[gbase[b] + (i - lo)] = val;
    }
}

// ---------------- place: per-bucket CSR finalize (XCD-local writes) ----------
__global__ __launch_bounds__(256) void place_edges(
    const int* __restrict__ bcnt, const int* __restrict__ staged,
    int* __restrict__ esrc, int* __restrict__ off, int* __restrict__ cnt,
    float* __restrict__ dinv, int n)
{
    __shared__ int cntL[256];
    __shared__ int scn[256];
    __shared__ int curL[256];
    int b = blockIdx.x;
    int tid = threadIdx.x;
    int node0 = b << 8;
    int nN = min(256, n - node0);
    int beg = b * CAP;
    int end = beg + bcnt[b];

    cntL[tid] = 0;
    __syncthreads();
    for (int i = beg + tid; i < end; i += 256)
        atomicAdd(&cntL[((unsigned)staged[i]) >> 24], 1);
    __syncthreads();
    scn[tid] = cntL[tid];
    __syncthreads();
    for (int d = 1; d < 256; d <<= 1) {
        int x = (tid >= d) ? scn[tid - d] : 0;
        __syncthreads();
        scn[tid] += x;
        __syncthreads();
    }
    int lofs = (tid == 0) ? 0 : scn[tid - 1];
    if (tid < nN) {
        int node = node0 + tid;
        off[node] = beg + lofs;
        cnt[node] = cntL[tid];
        dinv[node] = rsqrtf((float)cntL[tid] + 1.0f);
    }
    curL[tid] = beg + lofs;
    __syncthreads();
    for (int i = beg + tid; i < end; i += 256) {
        int u = staged[i];
        int pos = atomicAdd(&curL[((unsigned)u) >> 24], 1);
        esrc[pos] = u & 0x00FFFFFF;
    }
}

// ---------------- W prep bodies ----------------
template<int K, int FOUT>
__device__ __forceinline__ void prep_body3(
    const float* __restrict__ W, unsigned short* __restrict__ blob, int t)
{
    constexpr int CT = FOUT / 16;
    int lane = t & 63;
    int ct   = (t >> 6) % CT;
    int ks   = (t >> 6) / CT;
    int col  = ct * 16 + (lane & 15);
    int k0   = ks * 32 + (lane >> 4) * 8;

    union { bf16x8 v; unsigned short e[8]; } u;
#pragma unroll
    for (int j = 0; j < 8; ++j) {
        int kp = k0 + j;
        unsigned short r;
        if (kp < 2 * K) {
            int k = (kp < K) ? kp : kp - K;
            r = f2bf(W[k * FOUT + col]);
        } else {
            float f = W[(kp - 2 * K) * FOUT + col];
            unsigned short h = f2bf(f);
            r = f2bf(f - bf2f(h));
        }
        u.e[j] = r;
    }
    *reinterpret_cast<bf16x8*>(blob + (size_t)t * 8) = u.v;
}

template<int K, int FOUT>
__device__ __forceinline__ void prep_body2(
    const float* __restrict__ W, unsigned short* __restrict__ blob, int t)
{
    constexpr int CT = FOUT / 16;
    int lane = t & 63;
    int ct   = (t >> 6) % CT;
    int ks   = (t >> 6) / CT;
    int col  = ct * 16 + (lane & 15);
    int k0   = ks * 32 + (lane >> 4) * 8;

    union { bf16x8 v; unsigned short e[8]; } u;
#pragma unroll
    for (int j = 0; j < 8; ++j) {
        int kp = k0 + j;
        unsigned short r;
        if (kp < K) {
            r = f2bf(W[kp * FOUT + col]);
        } else {
            float f = W[(kp - K) * FOUT + col];
            unsigned short h = f2bf(f);
            r = f2bf(f - bf2f(h));
        }
        u.e[j] = r;
    }
    *reinterpret_cast<bf16x8*>(blob + (size_t)t * 8) = u.v;
}

__global__ __launch_bounds__(256) void prep_all(
    const float* __restrict__ W1, const float* __restrict__ W2,
    const float* __restrict__ W3, unsigned short* __restrict__ b1,
    unsigned short* __restrict__ b2, unsigned short* __restrict__ b3,
    int* __restrict__ bcur)
{
    int t = blockIdx.x * 256 + threadIdx.x;
    if (t < 3072)              prep_body3<128, 64>(W1, b1, t);
    else if (t < 3584)         prep_body2<64, 32>(W2, b2, t - 3072);
    else if (t < 3712)         prep_body2<32, 16>(W3, b3, t - 3584);
    else if (t < 3712 + K_BKT) bcur[t - 3712] = 0;
}

// ---------------- MFMA GEMM (f32 input, triple-K), 32-row tiles --------------
// wave w: row-half (w&1), col-half (w>>1) -> 2 col-tiles of 16.
template<int K, int FOUT>
__global__ __launch_bounds__(256) void gemm_mfma(
    const float* __restrict__ h, const unsigned short* __restrict__ wtb,
    const float* __restrict__ dinv, unsigned short* __restrict__ hw, int n)
{
    constexpr int PAD = 8;
    constexpr int LDA = 2 * K + PAD;     // 264 -> 16.9 KB LDS
    constexpr int CT  = FOUT / 16;       // 4
    constexpr int KS  = (3 * K) / 32;    // 12
    __shared__ unsigned short As[32 * LDA];

    const int tid  = threadIdx.x;
    const int row0 = blockIdx.x * 32;

    constexpr int QK = K / 4;
    for (int i = tid; i < 32 * QK; i += 256) {
        int r = i / QK;
        int q = i % QK;
        int g = row0 + r;
        float4 v;
        if (g < n) v = *reinterpret_cast<const float4*>(h + (size_t)g * K + q * 4);
        else       v = make_float4(0.f, 0.f, 0.f, 0.f);
        ushort4 hi, lo;
        hi.x = f2bf(v.x); lo.x = f2bf(v.x - bf2f(hi.x));
        hi.y = f2bf(v.y); lo.y = f2bf(v.y - bf2f(hi.y));
        hi.z = f2bf(v.z); lo.z = f2bf(v.z - bf2f(hi.z));
        hi.w = f2bf(v.w); lo.w = f2bf(v.w - bf2f(hi.w));
        *reinterpret_cast<ushort4*>(&As[r * LDA + q * 4])     = hi;
        *reinterpret_cast<ushort4*>(&As[r * LDA + K + q * 4]) = lo;
    }
    __syncthreads();

    const int wave = tid >> 6;
    const int lane = tid & 63;
    const int l15  = lane & 15;
    const int kgrp = (lane >> 4) * 8;
    const int rw   = wave & 1;           // row half
    const int chf  = wave >> 1;          // col half
    const int arow = rw * 16 + l15;

    const unsigned short* wlane = wtb + lane * 8;

    f32x4 acc[2];
    acc[0] = (f32x4){0.f, 0.f, 0.f, 0.f};
    acc[1] = (f32x4){0.f, 0.f, 0.f, 0.f};

#pragma unroll
    for (int ks = 0; ks < KS; ++ks) {
        int kp = ks * 32 + kgrp;
        int ka = (kp >= 2 * K) ? kp - 2 * K : kp;
        bf16x8 a = *reinterpret_cast<const bf16x8*>(&As[arow * LDA + ka]);
#pragma unroll
        for (int hh = 0; hh < 2; ++hh) {
            int ct = chf * 2 + hh;
            bf16x8 b = *reinterpret_cast<const bf16x8*>(wlane + (ks * CT + ct) * 512);
            acc[hh] = __builtin_amdgcn_mfma_f32_16x16x32_bf16(a, b, acc[hh], 0, 0, 0);
        }
    }

    const int rbase = rw * 16 + (lane >> 4) * 4;
    float dv[4];
#pragma unroll
    for (int j = 0; j < 4; ++j) {
        int g = row0 + rbase + j;
        dv[j] = (g < n) ? dinv[g] : 0.f;
    }
#pragma unroll
    for (int hh = 0; hh < 2; ++hh) {
        int col = (chf * 2 + hh) * 16 + l15;
#pragma unroll
        for (int j = 0; j < 4; ++j) {
            int g = row0 + rbase + j;
            if (g < n) hw[(size_t)g * FOUT + col] = f2bf(acc[hh][j] * dv[j]);
        }
    }
}

// ---------------- fused: gather+BN+ReLU (64 nodes/block) -> LDS -> MFMA GEMM --
// NO inter-phase barrier: wave wv writes LDS rows [wv*16, wv*16+16) and its
// GEMM phase reads ONLY those rows (arow = wv*16 + l15). Same-wave LDS RAW is
// ordered by compiler-inserted lgkmcnt waits -> waves proceed independently.
template<int F, int FOUT2>
__global__ __launch_bounds__(256) void gather_gemm(
    const int* __restrict__ off, const int* __restrict__ cnt,
    const int* __restrict__ esrc, const float* __restrict__ dinv,
    const unsigned short* __restrict__ hwin, const float* __restrict__ bias,
    const float* __restrict__ g, const float* __restrict__ be,
    const float* __restrict__ m, const float* __restrict__ v,
    const unsigned short* __restrict__ wtb, unsigned short* __restrict__ hwout,
    int n)
{
    constexpr int SG  = F / 4;
    constexpr int NSG = 64 / SG;
    constexpr int PAD = 8;
    constexpr int LDA = F + PAD;
    constexpr int CT  = FOUT2 / 16;
    constexpr int KS  = (2 * F) / 32;
    __shared__ unsigned short As[64 * LDA];

    const int tid   = threadIdx.x;
    const int wv    = tid >> 6;
    const int lane  = tid & 63;
    const int node0 = blockIdx.x * 64;
    const int sg = lane / SG;
    const int p  = lane % SG;

    // lane-parallel prefetch of off/cnt/dinv for the wave's 16 nodes
    int offv = 0, cntv = 0;
    float dnv = 0.f;
    {
        int nd = node0 + wv * 16 + (lane & 15);
        if (nd < n) {
            offv = off[nd];
            cntv = cnt[nd];
            dnv  = dinv[nd];
        }
    }

    for (int t = 0; t < 16; ++t) {
        int node = node0 + wv * 16 + t;
        int r = wv * 16 + t;
        int beg = __shfl(offv, t);
        int num = __shfl(cntv, t);
        float dn = __shfl(dnv, t);
        float sx = 0.f, sy = 0.f, sz = 0.f, sw = 0.f;
        if (node < n) {
            int j = sg;
            for (; j + NSG < num; j += 2 * NSG) {
                int s0 = esrc[beg + j];
                int s1 = esrc[beg + j + NSG];
                ushort4 a = *reinterpret_cast<const ushort4*>(hwin + (size_t)s0 * F + 4 * p);
                ushort4 b = *reinterpret_cast<const ushort4*>(hwin + (size_t)s1 * F + 4 * p);
                sx += bf2f(a.x) + bf2f(b.x);
                sy += bf2f(a.y) + bf2f(b.y);
                sz += bf2f(a.z) + bf2f(b.z);
                sw += bf2f(a.w) + bf2f(b.w);
            }
            if (j < num) {
                int s0 = esrc[beg + j];
                ushort4 a = *reinterpret_cast<const ushort4*>(hwin + (size_t)s0 * F + 4 * p);
                sx += bf2f(a.x); sy += bf2f(a.y); sz += bf2f(a.z); sw += bf2f(a.w);
            }
            if (sg == 0) {   // self-loop (hwin prescaled by dinv)
                ushort4 a = *reinterpret_cast<const ushort4*>(hwin + (size_t)node * F + 4 * p);
                sx += bf2f(a.x); sy += bf2f(a.y); sz += bf2f(a.z); sw += bf2f(a.w);
            }
        }
#pragma unroll
        for (int d = SG; d < 64; d <<= 1) {
            sx += __shfl_xor(sx, d);
            sy += __shfl_xor(sy, d);
            sz += __shfl_xor(sz, d);
            sw += __shfl_xor(sw, d);
        }
        if (sg == 0) {
            float y0 = 0.f, y1 = 0.f, y2 = 0.f, y3 = 0.f;
            int c0 = 4 * p;
            if (node < n) {
                float4 gg = *reinterpret_cast<const float4*>(g + c0);
                float4 vv = *reinterpret_cast<const float4*>(v + c0);
                float4 bb = *reinterpret_cast<const float4*>(bias + c0);
                float4 mm = *reinterpret_cast<const float4*>(m + c0);
                float4 ee = *reinterpret_cast<const float4*>(be + c0);
                y0 = fmaxf(gg.x * rsqrtf(vv.x + BN_EPS) * (dn * sx + bb.x - mm.x) + ee.x, 0.f);
                y1 = fmaxf(gg.y * rsqrtf(vv.y + BN_EPS) * (dn * sy + bb.y - mm.y) + ee.y, 0.f);
                y2 = fmaxf(gg.z * rsqrtf(vv.z + BN_EPS) * (dn * sz + bb.z - mm.z) + ee.z, 0.f);
                y3 = fmaxf(gg.w * rsqrtf(vv.w + BN_EPS) * (dn * sw + bb.w - mm.w) + ee.w, 0.f);
            }
            ushort4 pk;
            pk.x = f2bf(y0); pk.y = f2bf(y1); pk.z = f2bf(y2); pk.w = f2bf(y3);
            *reinterpret_cast<ushort4*>(&As[r * LDA + c0]) = pk;
        }
    }
    // no barrier: GEMM phase below reads only this wave's 16 rows.

    // ---- GEMM phase: As(own 16 rows x F bf16) @ W -> hwout, prescaled by dinv
    const int l15  = lane & 15;
    const int kgrp = (lane >> 4) * 8;
    const int arow = wv * 16 + l15;
    const unsigned short* wlane = wtb + lane * 8;

    f32x4 acc[CT];
#pragma unroll
    for (int ct = 0; ct < CT; ++ct) acc[ct] = (f32x4){0.f, 0.f, 0.f, 0.f};

#pragma unroll
    for (int ks = 0; ks < KS; ++ks) {
        int kp = ks * 32 + kgrp;
        int ka = (kp >= F) ? kp - F : kp;
        bf16x8 a = *reinterpret_cast<const bf16x8*>(&As[arow * LDA + ka]);
#pragma unroll
        for (int ct = 0; ct < CT; ++ct) {
            bf16x8 b = *reinterpret_cast<const bf16x8*>(wlane + (ks * CT + ct) * 512);
            acc[ct] = __builtin_amdgcn_mfma_f32_16x16x32_bf16(a, b, acc[ct], 0, 0, 0);
        }
    }

    const int rbase = wv * 16 + (lane >> 4) * 4;
    float dv[4];
#pragma unroll
    for (int j = 0; j < 4; ++j) {
        int gr = node0 + rbase + j;
        dv[j] = (gr < n) ? dinv[gr] : 0.f;
    }
#pragma unroll
    for (int ct = 0; ct < CT; ++ct) {
#pragma unroll
        for (int j = 0; j < 4; ++j) {
            int gr = node0 + rbase + j;
            if (gr < n) hwout[(size_t)gr * FOUT2 + ct * 16 + l15] = f2bf(acc[ct][j] * dv[j]);
        }
    }
}

// ---------------- layer-3 gather fused with FC(16->8)+sigmoid ----------------
__global__ __launch_bounds__(256) void gather_bn_relu_fc(
    const int* __restrict__ off, const int* __restrict__ cnt,
    const int* __restrict__ esrc, const float* __restrict__ dinv,
    const unsigned short* __restrict__ hw, const float* __restrict__ bias,
    const float* __restrict__ g, const float* __restrict__ be,
    const float* __restrict__ m, const float* __restrict__ v,
    const float* __restrict__ fcW, const float* __restrict__ fcb,
    float* __restrict__ out, int n)
{
    constexpr int F = 16, SG = 4, NSG = 16;
    __shared__ float WsF[128];
    __shared__ float bsF[8];
    __shared__ float ybuf[4][16];

    int tid = threadIdx.x;
    if (tid < 128) WsF[tid] = fcW[tid];
    if (tid < 8)   bsF[tid] = fcb[tid];
    __syncthreads();   // WsF/bsF cross-wave: barrier required

    int node = (blockIdx.x * 256 + tid) >> 6;
    int wv   = tid >> 6;
    int lane = tid & 63;
    bool act = node < n;

    if (act) {
        int sg = lane / SG;
        int p  = lane % SG;
        int beg = off[node];
        int num = cnt[node];

        float sx = 0.f, sy = 0.f, sz = 0.f, sw = 0.f;
        int j = sg;
        for (; j + NSG < num; j += 2 * NSG) {
            int s0 = esrc[beg + j];
            int s1 = esrc[beg + j + NSG];
            ushort4 a = *reinterpret_cast<const ushort4*>(hw + (size_t)s0 * F + 4 * p);
            ushort4 b = *reinterpret_cast<const ushort4*>(hw + (size_t)s1 * F + 4 * p);
            sx += bf2f(a.x) + bf2f(b.x);
            sy += bf2f(a.y) + bf2f(b.y);
            sz += bf2f(a.z) + bf2f(b.z);
            sw += bf2f(a.w) + bf2f(b.w);
        }
        if (j < num) {
            int s0 = esrc[beg + j];
            ushort4 a = *reinterpret_cast<const ushort4*>(hw + (size_t)s0 * F + 4 * p);
            sx += bf2f(a.x); sy += bf2f(a.y); sz += bf2f(a.z); sw += bf2f(a.w);
        }
        if (sg == 0) {
            ushort4 a = *reinterpret_cast<const ushort4*>(hw + (size_t)node * F + 4 * p);
            sx += bf2f(a.x); sy += bf2f(a.y); sz += bf2f(a.z); sw += bf2f(a.w);
        }

#pragma unroll
        for (int d = SG; d < 64; d <<= 1) {
            sx += __shfl_xor(sx, d);
            sy += __shfl_xor(sy, d);
            sz += __shfl_xor(sz, d);
            sw += __shfl_xor(sw, d);
        }

        if (sg == 0) {
            int c0 = 4 * p;
            float dn = dinv[node];
            ybuf[wv][c0+0] = fmaxf(g[c0+0] * rsqrtf(v[c0+0] + BN_EPS) * (dn * sx + bias[c0+0] - m[c0+0]) + be[c0+0], 0.f);
            ybuf[wv][c0+1] = fmaxf(g[c0+1] * rsqrtf(v[c0+1] + BN_EPS) * (dn * sy + bias[c0+1] - m[c0+1]) + be[c0+1], 0.f);
            ybuf[wv][c0+2] = fmaxf(g[c0+2] * rsqrtf(v[c0+2] + BN_EPS) * (dn * sz + bias[c0+2] - m[c0+2]) + be[c0+2], 0.f);
            ybuf[wv][c0+3] = fmaxf(g[c0+3] * rsqrtf(v[c0+3] + BN_EPS) * (dn * sw + bias[c0+3] - m[c0+3]) + be[c0+3], 0.f);
        }
    }
    // no barrier: ybuf[wv] is written and read by the SAME wave (lgkmcnt-ordered).

    if (act && lane < 8) {
        float o = bsF[lane];
#pragma unroll
        for (int k = 0; k < 16; ++k) o += ybuf[wv][k] * WsF[k * 8 + lane];
        out[(size_t)node * 8 + lane] = 1.0f / (1.0f + expf(-o));
    }
}

// ---------------- launch ----------------
extern "C" void kernel_launch(void* const* d_in, const int* in_sizes, int n_in,
                              void* d_out, int out_size, void* d_ws, size_t ws_size,
                              hipStream_t stream) {
    const float* x   = (const float*)d_in[0];
    const int*   ei  = (const int*)  d_in[1];   // [2, E]: src row then dst row
    const float* W1  = (const float*)d_in[2];
    const float* b1  = (const float*)d_in[3];
    const float* g1  = (const float*)d_in[4];
    const float* be1 = (const float*)d_in[5];
    const float* m1  = (const float*)d_in[6];
    const float* v1  = (const float*)d_in[7];
    const float* W2  = (const float*)d_in[8];
    const float* b2  = (const float*)d_in[9];
    const float* g2  = (const float*)d_in[10];
    const float* be2 = (const float*)d_in[11];
    const float* m2  = (const float*)d_in[12];
    const float* v2  = (const float*)d_in[13];
    const float* W3  = (const float*)d_in[14];
    const float* b3  = (const float*)d_in[15];
    const float* g3  = (const float*)d_in[16];
    const float* be3 = (const float*)d_in[17];
    const float* m3  = (const float*)d_in[18];
    const float* v3  = (const float*)d_in[19];
    const float* fcW = (const float*)d_in[20];
    const float* fcb = (const float*)d_in[21];
    float* out = (float*)d_out;

    const int* src = ei;
    const int* dst = ei + NE;

    char* w = (char*)d_ws;
    float* dinv  = (float*)(w + 0);                   // N f32
    int*   cnt   = (int*)  (w + (512 << 10));         // N i32
    int*   off   = (int*)  (w + (1024 << 10));        // N i32
    int*   bcur  = (int*)  (w + (1536 << 10));        // K_BKT i32
    int*   staged= (int*)  (w + (2u << 20));          // K_BKT*CAP i32 = 9.6 MB
    int*   esrc  = (int*)  (w + (12u << 20));         // K_BKT*CAP i32 = 9.6 MB
    unsigned short* wt1 = (unsigned short*)(w + (22u << 20)); // 48 KB blob (triple-K)
    unsigned short* wt2 = wt1 + 24576;                         // 8 KB blob (double-K)
    unsigned short* wt3 = wt2 + 4096;                          // 2 KB blob (double-K)
    unsigned short* hw1 = (unsigned short*)(w + (24u << 20)); // N*64 bf16 = 12.8 MB
    unsigned short* hw2 = (unsigned short*)(w + (38u << 20)); // N*32 bf16 = 6.4 MB
    unsigned short* hw3 = (unsigned short*)(w + (46u << 20)); // N*16 bf16 = 3.2 MB

    // ---- W blobs + bcur zero (one kernel) ----
    prep_all<<<(3712 + K_BKT + 255) / 256, 256, 0, stream>>>(
        W1, W2, W3, wt1, wt2, wt3, bcur);

    // ---- CSR build: partition (fixed-capacity buckets) -> place ----
    partition_edges<<<(NE + CH - 1) / CH, 256, 0, stream>>>(src, dst, bcur, staged, NE);
    place_edges<<<K_BKT, 256, 0, stream>>>(bcur, staged, esrc, off, cnt, dinv, NN);

    const int GB = (NN + 63) / 64;          // 64 nodes per block (gather_gemm)
    const int GG = (NN * 64 + 255) / 256;   // one wave per node (layer-3)

    // layer 1 transform (MFMA, f32 in, triple-K, 32-row tiles)
    gemm_mfma<128, 64><<<(NN + 31) / 32, 256, 0, stream>>>(x, wt1, dinv, hw1, NN);

    // layer 1 gather + BN + ReLU -> LDS -> MFMA (h1 @ W2) -> hw2
    gather_gemm<64, 32><<<GB, 256, 0, stream>>>(
        off, cnt, esrc, dinv, hw1, b1, g1, be1, m1, v1, wt2, hw2, NN);

    // layer 2 gather + BN + ReLU -> LDS -> MFMA (h2 @ W3) -> hw3
    gather_gemm<32, 16><<<GB, 256, 0, stream>>>(
        off, cnt, esrc, dinv, hw2, b2, g2, be2, m2, v2, wt3, hw3, NN);

    // layer 3 gather fused with FC + sigmoid
    gather_bn_relu_fc<<<GG, 256, 0, stream>>>(
        off, cnt, esrc, dinv, hw3, b3, g3, be3, m3, v3, fcW, fcb, out, NN);
}